// Round 7
// baseline (62.280 us; speedup 1.0000x reference)
//
#include <hip/hip_runtime.h>
#include <math.h>

#define BB 64
#define TT 2048
#define DD 512
#define HH 512
#define NC 16                 // k1 chunks: CHUNK=128 rows/block, 1024 blocks
#define CHUNK (TT / NC)
#define TH 8.0f               // defer-rescale threshold

// ---------------------------------------------------------------------------
// Kernel 1: fused scores + deferred-rescale online-softmax + partial context.
// grid (NC, B), block 256 (4 waves). Wave w owns 32 contiguous rows,
// processed as 16 batches of 2 rows with ping-pong single-ahead prefetch.
// (round-6 bug: loop ran 32 batches = 64 rows/wave -> OOB fault. Now 16.)
// ---------------------------------------------------------------------------
__global__ __launch_bounds__(256) void k1_partial(
    const float* __restrict__ x, const float* __restrict__ enc,
    const int* __restrict__ step_ptr,
    float* __restrict__ ws_m, float* __restrict__ ws_l, float* __restrict__ ws_c)
{
    const int chunk = blockIdx.x;
    const int b     = blockIdx.y;
    const int tid   = threadIdx.x;
    const int w     = tid >> 6;
    const int lane  = tid & 63;
    const int step  = *step_ptr;
    const int trow0 = chunk * CHUNK + w * 32;   // wave's first row (32 rows/wave)

    const float4* xr = (const float4*)(x + (size_t)b * DD);
    const float4 xa = xr[lane];
    const float4 xb = xr[64 + lane];

    // row r: halfA rp[r*128], halfB rp[r*128+64]
    const float4* __restrict__ rp =
        (const float4*)(enc + (size_t)b * TT * DD) + (size_t)trow0 * 128 + lane;

    float m = -1e30f, l = 0.f;
    float4 ca = make_float4(0.f,0.f,0.f,0.f), cb = make_float4(0.f,0.f,0.f,0.f);

    // ping-pong staging: parity holds rows {bat*2, bat*2+1}
    float4 A[2][2], Bv[2][2];
    A[0][0]  = rp[0 * 128];      A[0][1]  = rp[1 * 128];
    Bv[0][0] = rp[0 * 128 + 64]; Bv[0][1] = rp[1 * 128 + 64];

    #pragma unroll 4
    for (int jj = 0; jj < 8; ++jj) {              // 16 batches of 2 rows = 32 rows
        #pragma unroll
        for (int par = 0; par < 2; ++par) {       // static parity
            const int bat = jj * 2 + par;         // 0..15
            const int nx  = par ^ 1;
            if (bat < 15) {                       // prefetch next 2-row batch
                A[nx][0]  = rp[((bat + 1) * 2 + 0) * 128];
                A[nx][1]  = rp[((bat + 1) * 2 + 1) * 128];
                Bv[nx][0] = rp[((bat + 1) * 2 + 0) * 128 + 64];
                Bv[nx][1] = rp[((bat + 1) * 2 + 1) * 128 + 64];
            }
            // 2 independent dot products
            float s[2];
            #pragma unroll
            for (int r = 0; r < 2; ++r) {
                const float4 ea = A[par][r], eb = Bv[par][r];
                s[r] = ea.x*xa.x + ea.y*xa.y + ea.z*xa.z + ea.w*xa.w
                     + eb.x*xb.x + eb.y*xb.y + eb.z*xb.z + eb.w*xb.w;
            }
            #pragma unroll
            for (int off = 32; off; off >>= 1) {
                s[0] += __shfl_xor(s[0], off, 64);
                s[1] += __shfl_xor(s[1], off, 64);
            }
            #pragma unroll
            for (int r = 0; r < 2; ++r)
                if (trow0 + bat * 2 + r == step) s[r] = -1e30f;

            const float bm = fmaxf(s[0], s[1]);
            if (bm > m + TH) {                    // wave-uniform, rare
                const float sc = __expf(m - bm);
                l *= sc;
                ca.x *= sc; ca.y *= sc; ca.z *= sc; ca.w *= sc;
                cb.x *= sc; cb.y *= sc; cb.z *= sc; cb.w *= sc;
                m = bm;
            }
            const float w0 = __expf(s[0] - m);
            const float w1 = __expf(s[1] - m);
            l += w0 + w1;
            ca.x = fmaf(w0, A[par][0].x, fmaf(w1, A[par][1].x, ca.x));
            ca.y = fmaf(w0, A[par][0].y, fmaf(w1, A[par][1].y, ca.y));
            ca.z = fmaf(w0, A[par][0].z, fmaf(w1, A[par][1].z, ca.z));
            ca.w = fmaf(w0, A[par][0].w, fmaf(w1, A[par][1].w, ca.w));
            cb.x = fmaf(w0, Bv[par][0].x, fmaf(w1, Bv[par][1].x, cb.x));
            cb.y = fmaf(w0, Bv[par][0].y, fmaf(w1, Bv[par][1].y, cb.y));
            cb.z = fmaf(w0, Bv[par][0].z, fmaf(w1, Bv[par][1].z, cb.z));
            cb.w = fmaf(w0, Bv[par][0].w, fmaf(w1, Bv[par][1].w, cb.w));
        }
    }

    // ---- block combine of the 4 wave-partials via LDS ----
    __shared__ float ls_m[4], ls_l[4];
    __shared__ float ls_c[4][DD];
    if (lane == 0) { ls_m[w] = m; ls_l[w] = l; }
    {
        float* cw = ls_c[w];
        const int d0 = lane * 4;
        cw[d0 + 0] = ca.x; cw[d0 + 1] = ca.y; cw[d0 + 2] = ca.z; cw[d0 + 3] = ca.w;
        cw[256 + d0 + 0] = cb.x; cw[256 + d0 + 1] = cb.y;
        cw[256 + d0 + 2] = cb.z; cw[256 + d0 + 3] = cb.w;
    }
    __syncthreads();

    const float M = fmaxf(fmaxf(ls_m[0], ls_m[1]), fmaxf(ls_m[2], ls_m[3]));
    const float f0 = __expf(ls_m[0] - M);
    const float f1 = __expf(ls_m[1] - M);
    const float f2 = __expf(ls_m[2] - M);
    const float f3 = __expf(ls_m[3] - M);
    const float L = ls_l[0] * f0 + ls_l[1] * f1 + ls_l[2] * f2 + ls_l[3] * f3;

    const int bc = b * NC + chunk;
    for (int d = tid; d < DD; d += 256) {
        const float v = ls_c[0][d] * f0 + ls_c[1][d] * f1
                      + ls_c[2][d] * f2 + ls_c[3][d] * f3;
        ws_c[(size_t)bc * DD + d] = v;
    }
    if (tid == 0) { ws_m[bc] = M; ws_l[bc] = L; }
}

// ---------------------------------------------------------------------------
// Kernel 1b: merge NC partials -> normalized context ctx[B][DD].
// grid (B, 2): block (b, half) handles 256 d -> 128 blocks.
// ---------------------------------------------------------------------------
__global__ __launch_bounds__(256) void k1b_merge(
    const float* __restrict__ ws_m, const float* __restrict__ ws_l,
    const float* __restrict__ ws_c, float* __restrict__ ctx)
{
    const int b    = blockIdx.x;
    const int half = blockIdx.y;
    const int tid  = threadIdx.x;
    __shared__ float fac[NC];

    float M = -1e30f;
    #pragma unroll
    for (int i = 0; i < NC; ++i) M = fmaxf(M, ws_m[b * NC + i]);
    float L = 0.f;
    #pragma unroll
    for (int i = 0; i < NC; ++i) L += ws_l[b * NC + i] * __expf(ws_m[b * NC + i] - M);
    const float inv = 1.f / L;
    if (tid < NC) fac[tid] = __expf(ws_m[b * NC + tid] - M) * inv;
    __syncthreads();

    const int d = half * 256 + tid;
    float acc = 0.f;
    #pragma unroll
    for (int i = 0; i < NC; ++i)
        acc = fmaf(ws_c[(size_t)(b * NC + i) * DD + d], fac[i], acc);
    ctx[(size_t)b * DD + d] = acc;
}

// ---------------------------------------------------------------------------
// Kernel 2: gated gemm with 8-b W reuse.
// grid (16, 8): block covers 8 float4-cols (32 h) x 8 b.
// concat in LDS: padded-segment layout, bijective:
//   cidx(k,bb) = (k>>5)*260 + (k&31)*8 + bb
// ---------------------------------------------------------------------------
#define COLS 8
__device__ __forceinline__ int cidx(int k, int bb) {
    return (k >> 5) * 260 + (k & 31) * 8 + bb;
}

__global__ __launch_bounds__(256) void k2_gemm(
    const float* __restrict__ x, const float* __restrict__ ctx,
    const float* __restrict__ W, const float* __restrict__ bias,
    float* __restrict__ out)
{
    const int g   = blockIdx.x;     // 0..15
    const int bg  = blockIdx.y;     // 0..7
    const int tid = threadIdx.x;

    __shared__ float  con[32 * 260];        // 8320 floats, padded segments
    __shared__ float4 part[4][COLS][8];

    const float4* x4 = (const float4*)x;
    const float4* c4 = (const float4*)ctx;

    for (int idx = tid; idx < 2048; idx += 256) {
        const int bb = idx >> 8, k4 = idx & 255;
        const int b  = bg * 8 + bb;
        const float4 v = (k4 < 128) ? x4[(size_t)b * 128 + k4]
                                    : c4[(size_t)b * 128 + (k4 - 128)];
        const int k = k4 * 4;
        con[cidx(k + 0, bb)] = v.x;
        con[cidx(k + 1, bb)] = v.y;
        con[cidx(k + 2, bb)] = v.z;
        con[cidx(k + 3, bb)] = v.w;
    }
    __syncthreads();

    const int cl   = tid & 7;               // col within block
    const int kseg = tid >> 3;              // 0..31, 32 k each
    const int col4 = g * COLS + cl;
    const float4* Wp = (const float4*)W + (size_t)(kseg * 32) * 128 + col4;

    float4 acc[8];
    #pragma unroll
    for (int bb = 0; bb < 8; ++bb) acc[bb] = make_float4(0.f,0.f,0.f,0.f);

    #pragma unroll 4
    for (int kk = 0; kk < 32; ++kk) {
        const float4 wv = Wp[(size_t)kk * 128];
        const int k = kseg * 32 + kk;
        const float4 c0 = *(const float4*)&con[cidx(k, 0)];   // bb 0..3
        const float4 c1 = *(const float4*)&con[cidx(k, 4)];   // bb 4..7
        const float cv[8] = {c0.x, c0.y, c0.z, c0.w, c1.x, c1.y, c1.z, c1.w};
        #pragma unroll
        for (int bb = 0; bb < 8; ++bb) {
            acc[bb].x = fmaf(cv[bb], wv.x, acc[bb].x);
            acc[bb].y = fmaf(cv[bb], wv.y, acc[bb].y);
            acc[bb].z = fmaf(cv[bb], wv.z, acc[bb].z);
            acc[bb].w = fmaf(cv[bb], wv.w, acc[bb].w);
        }
    }

    // in-wave reduce over the 8 ksegs resident in each wave (lane = kseg*8+cl)
    #pragma unroll
    for (int off = 8; off <= 32; off <<= 1) {
        #pragma unroll
        for (int bb = 0; bb < 8; ++bb) {
            acc[bb].x += __shfl_xor(acc[bb].x, off, 64);
            acc[bb].y += __shfl_xor(acc[bb].y, off, 64);
            acc[bb].z += __shfl_xor(acc[bb].z, off, 64);
            acc[bb].w += __shfl_xor(acc[bb].w, off, 64);
        }
    }
    const int wv_ = tid >> 6, lane = tid & 63;
    if (lane < 8) {
        #pragma unroll
        for (int bb = 0; bb < 8; ++bb) part[wv_][lane][bb] = acc[bb];
    }
    __syncthreads();

    if (tid < 64) {
        const int bb = tid >> 3, cl2 = tid & 7;
        float4 r = part[0][cl2][bb];
        #pragma unroll
        for (int ww = 1; ww < 4; ++ww) {
            const float4 p = part[ww][cl2][bb];
            r.x += p.x; r.y += p.y; r.z += p.z; r.w += p.w;
        }
        const int c4i = g * COLS + cl2;
        const int h   = c4i * 4;
        const int b   = bg * 8 + bb;
        const float4 bv = ((const float4*)bias)[c4i];
        const float xv0 = con[cidx(h + 0, bb)];
        const float xv1 = con[cidx(h + 1, bb)];
        const float xv2 = con[cidx(h + 2, bb)];
        const float xv3 = con[cidx(h + 3, bb)];
        float4 o;
        o.x = xv0 / (1.f + __expf(-(r.x + bv.x)));
        o.y = xv1 / (1.f + __expf(-(r.y + bv.y)));
        o.z = xv2 / (1.f + __expf(-(r.z + bv.z)));
        o.w = xv3 / (1.f + __expf(-(r.w + bv.w)));
        ((float4*)out)[(size_t)b * 128 + c4i] = o;
    }
}

// ---------------------------------------------------------------------------
extern "C" void kernel_launch(void* const* d_in, const int* in_sizes, int n_in,
                              void* d_out, int out_size, void* d_ws, size_t ws_size,
                              hipStream_t stream) {
    const float* x    = (const float*)d_in[0];
    const float* enc  = (const float*)d_in[1];
    const float* W    = (const float*)d_in[2];
    const float* bias = (const float*)d_in[3];
    const int*   step = (const int*)d_in[4];
    float* out = (float*)d_out;
    float* ws  = (float*)d_ws;

    float* ws_m = ws;                                 // [B*NC]
    float* ws_l = ws_m + (size_t)BB * NC;             // [B*NC]
    float* ws_c = ws_l + (size_t)BB * NC;             // [B*NC*DD]
    float* ctx  = ws_c + (size_t)BB * NC * DD;        // [B*DD]

    k1_partial<<<dim3(NC, BB), 256, 0, stream>>>(x, enc, step, ws_m, ws_l, ws_c);
    k1b_merge<<<dim3(BB, 2), 256, 0, stream>>>(ws_m, ws_l, ws_c, ctx);
    k2_gemm<<<dim3(16, 8), 256, 0, stream>>>(x, ctx, W, bias, out);
}